// Round 5
// baseline (30732.877 us; speedup 1.0000x reference)
//
#include <hip/hip_runtime.h>
#include <hip/hip_bf16.h>

#define BATCH 16384
#define TSTEPS 101
#define HDIM 512
#define GDIM 2048  // 4*H
#define NBLK 512

typedef __attribute__((ext_vector_type(8))) short s16x8;
typedef __attribute__((ext_vector_type(16))) float f32x16;
typedef __attribute__((ext_vector_type(4))) float f32x4;

__device__ __forceinline__ float sigm(float x){ return 1.0f/(1.0f + __expf(-x)); }
__device__ __forceinline__ float tanhx(float x){ float e=__expf(2.0f*x); return 1.0f - 2.0f/(e+1.0f); }

__device__ __forceinline__ void gload16(const void* g, void* l){
  __builtin_amdgcn_global_load_lds((const __attribute__((address_space(1))) unsigned int*)g,
                                   (__attribute__((address_space(3))) unsigned int*)l, 16, 0, 0);
}

// device-scope grid barrier (generation-based). All NBLK blocks resident by construction:
// 0 LDS, <=256 VGPR (launch_bounds(256,2)) -> >=2 blocks/CU x 256 CUs = 512 slots.
__device__ __forceinline__ void gsync(unsigned* cnt, unsigned* gen){
  __syncthreads();
  if (threadIdx.x == 0){
    __threadfence();  // release: write back dirty L2 (h, c) to coherence point
    unsigned g = __hip_atomic_load(gen, __ATOMIC_RELAXED, __HIP_MEMORY_SCOPE_AGENT);
    unsigned prev = __hip_atomic_fetch_add(cnt, 1u, __ATOMIC_ACQ_REL, __HIP_MEMORY_SCOPE_AGENT);
    if (prev == NBLK - 1u){
      __hip_atomic_store(cnt, 0u, __ATOMIC_RELAXED, __HIP_MEMORY_SCOPE_AGENT);
      __hip_atomic_store(gen, g + 1u, __ATOMIC_RELEASE, __HIP_MEMORY_SCOPE_AGENT);
    } else {
      while (__hip_atomic_load(gen, __ATOMIC_ACQUIRE, __HIP_MEMORY_SCOPE_AGENT) == g){
        __builtin_amdgcn_s_sleep(8);
      }
    }
    __threadfence();  // acquire: invalidate stale L2 lines (other XCDs' h writes)
  }
  __syncthreads();
}

// Persistent LSTM: all 101 steps in one launch.
// 512 blocks x 256 threads (4 waves), >=2 blocks/CU. Block owns (panel of 256 rows,
// col-blocks {2jp, 2jp+1}); wave owns 64 rows x 128 gate-cols (4 gates x 32 hcols).
// K-loop is LDS-free: A/B fragments global->VGPR, register double-buffered, no barriers.
// MFMA 32x32x16 bf16; C/D map: col=lane&31, row=(reg&3)+8*(reg>>2)+4*(lane>>5).
__global__ __launch_bounds__(256, 2) void lstm_all(
    const float* __restrict__ bx,
    const float* __restrict__ Wih,
    const float* __restrict__ Whh,
    const float* __restrict__ bih,
    const float* __restrict__ bhh,
    const float* __restrict__ W1,
    __hip_bfloat16* __restrict__ wbf,
    __hip_bfloat16* __restrict__ w1bf,
    float* __restrict__ bcomb,
    __hip_bfloat16* __restrict__ hb0,
    __hip_bfloat16* __restrict__ hb1,
    float* __restrict__ cbuf,
    unsigned* cnt, unsigned* gen)
{
  const int tid = threadIdx.x, bid = blockIdx.x;

  // ---- prologue: weight conversion (replaces prep kernel) ----
  {
    int tg = bid*256 + tid;                 // 0..131071
    #pragma unroll
    for (int j = 0; j < 8; ++j){
      int i = tg + j*131072;
      wbf[i] = __float2bfloat16(Whh[i]);    // 4H x H
    }
    #pragma unroll
    for (int j = 0; j < 2; ++j){
      int i = tg + j*131072;
      w1bf[i] = __float2bfloat16(W1[i]);    // M x H
    }
    if (tg < GDIM) bcomb[tg] = bih[tg] + bhh[tg];
  }
  gsync(cnt, gen);

  const int l  = tid & 63, w = tid >> 6;
  const int lo = l & 31,  hi = l >> 5;

  const int xcd = bid & 7, s = bid >> 3;
  const int panel = xcd*8 + (s & 7);        // 0..63 ; panels XCD-pinned for L2 locality
  const int jp = s >> 3;                    // 0..7

  for (int t = 0; t < TSTEPS; ++t){
    const __hip_bfloat16* hin = (t & 1) ? hb1 : hb0;
    __hip_bfloat16*      hout = (t & 1) ? hb0 : hb1;

    #pragma unroll
    for (int tl = 0; tl < 2; ++tl){
      const int cb = jp*2 + tl;             // col-block 0..15 (32 hcols)
      f32x16 acc[4][2] = {};                // [gate][m-frag]

      if (t > 0){
        // per-lane fragment base pointers (A: row = base + lo; k-octet = hi)
        const __hip_bfloat16* pa0 = hin + (size_t)(panel*256 + w*64 + lo)*HDIM + hi*8;
        const __hip_bfloat16* pa1 = pa0 + (size_t)32*HDIM;
        const __hip_bfloat16* pb[4];
        #pragma unroll
        for (int g = 0; g < 4; ++g)
          pb[g] = wbf + (size_t)(g*HDIM + cb*32 + lo)*HDIM + hi*8;

        s16x8 av[2][2][2], bv[2][4][2];     // [buf][m][kk] / [buf][g][kk]
        #pragma unroll
        for (int kk = 0; kk < 2; ++kk){
          av[0][0][kk] = *(const s16x8*)(pa0 + kk*16);
          av[0][1][kk] = *(const s16x8*)(pa1 + kk*16);
          #pragma unroll
          for (int g = 0; g < 4; ++g) bv[0][g][kk] = *(const s16x8*)(pb[g] + kk*16);
        }
        #pragma unroll
        for (int kt = 0; kt < 16; ++kt){
          const int cur = kt & 1, nxt = cur ^ 1;
          if (kt < 15){
            const int ko = (kt + 1)*32;     // element offset; folds to imm byte offsets
            #pragma unroll
            for (int kk = 0; kk < 2; ++kk){
              av[nxt][0][kk] = *(const s16x8*)(pa0 + ko + kk*16);
              av[nxt][1][kk] = *(const s16x8*)(pa1 + ko + kk*16);
              #pragma unroll
              for (int g = 0; g < 4; ++g) bv[nxt][g][kk] = *(const s16x8*)(pb[g] + ko + kk*16);
            }
          }
          #pragma unroll
          for (int kk = 0; kk < 2; ++kk)
            #pragma unroll
            for (int g = 0; g < 4; ++g)
              #pragma unroll
              for (int m = 0; m < 2; ++m)
                acc[g][m] = __builtin_amdgcn_mfma_f32_32x32x16_bf16(
                    av[cur][m][kk], bv[cur][g][kk], acc[g][m], 0, 0, 0);
        }
      }

      // ---- epilogue: x-projection + bias + cell update ----
      float4 wv[4]; float bc4[4];
      const int colg = cb*32 + lo;
      #pragma unroll
      for (int g = 0; g < 4; ++g){
        int gc = g*HDIM + colg;
        wv[g]  = *(const float4*)(Wih + (size_t)gc*4);
        bc4[g] = bcomb[gc];
      }
      #pragma unroll
      for (int m = 0; m < 2; ++m){
        #pragma unroll
        for (int q = 0; q < 4; ++q){
          #pragma unroll
          for (int i2 = 0; i2 < 4; ++i2){
            const int reg = q*4 + i2;
            const int r = panel*256 + w*64 + m*32 + q*8 + hi*4 + i2;
            float4 xv = *(const float4*)(bx + ((size_t)r*TSTEPS + t)*4);
            float pi = acc[0][m][reg] + bc4[0] + xv.x*wv[0].x + xv.y*wv[0].y + xv.z*wv[0].z + xv.w*wv[0].w;
            float pf = acc[1][m][reg] + bc4[1] + xv.x*wv[1].x + xv.y*wv[1].y + xv.z*wv[1].z + xv.w*wv[1].w;
            float pg = acc[2][m][reg] + bc4[2] + xv.x*wv[2].x + xv.y*wv[2].y + xv.z*wv[2].z + xv.w*wv[2].w;
            float po = acc[3][m][reg] + bc4[3] + xv.x*wv[3].x + xv.y*wv[3].y + xv.z*wv[3].z + xv.w*wv[3].w;
            float iv = sigm(pi), fv = sigm(pf), gv = tanhx(pg), ov = sigm(po);
            size_t idx = (size_t)r*HDIM + colg;
            float cold = (t > 0) ? cbuf[idx] : 0.f;   // t=0: c0 = 0, don't read poison
            float cn = fv*cold + iv*gv;
            cbuf[idx] = cn;
            hout[idx] = __float2bfloat16(ov*tanhx(cn));
          }
        }
      }
    }
    if (t < TSTEPS - 1) gsync(cnt, gen);   // step boundary (kernel end syncs the last one)
  }
}

// x = relu(hT @ W1^T + b1), bf16 MFMA, fp32 out. Block 128x128, wave 32x128.
__global__ __launch_bounds__(256) void mlp1(const __hip_bfloat16* __restrict__ hT,
                                            const __hip_bfloat16* __restrict__ w1bf,
                                            const float* __restrict__ b1, float* __restrict__ xout){
  __shared__ short sA[128*64];
  __shared__ short sB[128*64];
  const int tid = threadIdx.x;
  const int l = tid & 63, w = tid >> 6;
  const int lr = l & 15, lk = l >> 4;
  const int r0 = blockIdx.x * 128, c0 = blockIdx.y * 128;

  f32x4 acc[2][8] = {};
  for (int k0 = 0; k0 < HDIM; k0 += 64){
    __syncthreads();
    #pragma unroll
    for (int i = 0; i < 4; ++i){
      int cch = i*256 + tid;
      int row = cch >> 3, kc = cch & 7;
      int kcs = kc ^ (row & 7);
      gload16(hT + (size_t)(r0 + row)*HDIM + k0 + kcs*8, &sA[cch*8]);
    }
    #pragma unroll
    for (int i = 0; i < 4; ++i){
      int cch = i*256 + tid;
      int row = cch >> 3, kc = cch & 7;
      int kcs = kc ^ (row & 7);
      gload16(w1bf + (size_t)(c0 + row)*HDIM + k0 + kcs*8, &sB[cch*8]);
    }
    __syncthreads();
    #pragma unroll
    for (int kk = 0; kk < 2; ++kk){
      s16x8 av[2];
      #pragma unroll
      for (int m = 0; m < 2; ++m){
        int row = w*32 + m*16 + lr;
        int slot = row*8 + ((kk*4 + lk) ^ (row & 7));
        av[m] = *(const s16x8*)&sA[slot*8];
      }
      #pragma unroll
      for (int n = 0; n < 8; ++n){
        int rB = n*16 + lr;
        int slot = rB*8 + ((kk*4 + lk) ^ (rB & 7));
        s16x8 bv = *(const s16x8*)&sB[slot*8];
        #pragma unroll
        for (int m = 0; m < 2; ++m)
          acc[m][n] = __builtin_amdgcn_mfma_f32_16x16x32_bf16(av[m], bv, acc[m][n], 0, 0, 0);
      }
    }
  }
  #pragma unroll
  for (int m = 0; m < 2; ++m){
    #pragma unroll
    for (int rg = 0; rg < 4; ++rg){
      int r = r0 + w*32 + m*16 + lk*4 + rg;
      #pragma unroll
      for (int n = 0; n < 8; ++n){
        int c = c0 + n*16 + lr;
        float v = acc[m][n][rg] + b1[c];
        xout[(size_t)r*HDIM + c] = v > 0.f ? v : 0.f;
      }
    }
  }
}

// out[b] = x[b,:] . W2[0:512] + a[b]*W2[512] + b2 ; one wave per row
__global__ __launch_bounds__(256) void mlp2(const float* __restrict__ x, const float* __restrict__ a,
                                            const float* __restrict__ W2, const float* __restrict__ b2,
                                            float* __restrict__ out){
  const int wi = threadIdx.x >> 6, l = threadIdx.x & 63;
  const int b = blockIdx.x*4 + wi;
  const float* xr = x + (size_t)b*HDIM;
  float4 v0 = *(const float4*)(xr + l*8);
  float4 v1 = *(const float4*)(xr + l*8 + 4);
  float4 w0 = *(const float4*)(W2 + l*8);
  float4 w1 = *(const float4*)(W2 + l*8 + 4);
  float s = v0.x*w0.x + v0.y*w0.y + v0.z*w0.z + v0.w*w0.w
          + v1.x*w1.x + v1.y*w1.y + v1.z*w1.z + v1.w*w1.w;
  #pragma unroll
  for (int off = 32; off > 0; off >>= 1) s += __shfl_down(s, off);
  if (l == 0) out[b] = s + a[b]*W2[HDIM] + b2[0];
}

extern "C" void kernel_launch(void* const* d_in, const int* in_sizes, int n_in,
                              void* d_out, int out_size, void* d_ws, size_t ws_size,
                              hipStream_t stream){
  const float* bx  = (const float*)d_in[0];
  const float* ba  = (const float*)d_in[1];
  const float* Wih = (const float*)d_in[2];
  const float* Whh = (const float*)d_in[3];
  const float* bih = (const float*)d_in[4];
  const float* bhh = (const float*)d_in[5];
  const float* W1  = (const float*)d_in[6];
  const float* b1  = (const float*)d_in[7];
  const float* W2  = (const float*)d_in[8];
  const float* b2  = (const float*)d_in[9];
  float* out = (float*)d_out;

  char* ws = (char*)d_ws;
  __hip_bfloat16* wbf   = (__hip_bfloat16*)(ws);              // 2 MB
  __hip_bfloat16* w1bf  = (__hip_bfloat16*)(ws + 2097152);    // 512 KB
  float*          bcomb = (float*)(ws + 2621440);             // 8 KB
  __hip_bfloat16* hb0   = (__hip_bfloat16*)(ws + 2629632);    // 16 MB
  __hip_bfloat16* hb1   = (__hip_bfloat16*)(ws + 19406848);   // 16 MB
  float*          cbuf  = (float*)(ws + 36184064);            // 32 MB
  unsigned*       sync  = (unsigned*)(ws + 69738496);         // 256 B (end ~66.6 MB)
  float*          xmlp  = cbuf;  // c dead after last step; reuse for MLP activations

  hipMemsetAsync(sync, 0, 256, stream);   // cnt=0, gen=0

  lstm_all<<<NBLK, 256, 0, stream>>>(bx, Wih, Whh, bih, bhh, W1,
                                     wbf, w1bf, bcomb, hb0, hb1, cbuf,
                                     sync, sync + 32);

  // t=100 wrote hout = hb1
  mlp1<<<dim3(128, 4), 256, 0, stream>>>(hb1, w1bf, b1, xmlp);
  mlp2<<<4096, 256, 0, stream>>>(xmlp, ba, W2, b2, out);
}

// Round 6
// 7040.097 us; speedup vs baseline: 4.3654x; 4.3654x over previous
//
#include <hip/hip_runtime.h>
#include <hip/hip_bf16.h>

#define BATCH 16384
#define TSTEPS 101
#define HDIM 512
#define GDIM 2048  // 4*H

typedef __attribute__((ext_vector_type(8))) short s16x8;
typedef __attribute__((ext_vector_type(16))) float f32x16;
typedef __attribute__((ext_vector_type(4))) float f32x4;

__device__ __forceinline__ float sigm(float x){ return 1.0f/(1.0f + __expf(-x)); }
__device__ __forceinline__ float tanhx(float x){ float e=__expf(2.0f*x); return 1.0f - 2.0f/(e+1.0f); }

__device__ __forceinline__ void gload16(const void* g, void* l){
  __builtin_amdgcn_global_load_lds((const __attribute__((address_space(1))) unsigned int*)g,
                                   (__attribute__((address_space(3))) unsigned int*)l, 16, 0, 0);
}

// gates = hin @ W_hh^T (+ x_t @ W_ih^T + b), then LSTM cell update.
// 512 blocks XCD-chunked: 64 row-panels (256 rows) x 8 col-quads (64 hcols x 4 gates).
// 512 threads = 8 waves; wave = 64 rows x 128 gatecols (4 gates x 32 hcols).
// BK=64, single-buffered 64KB LDS (A 256x64, B 256x64), XOR-swizzled, 2 syncs/K-tile.
// MFMA 32x32x16 bf16; C/D map: col=lane&31, row=(reg&3)+8*(reg>>2)+4*(lane>>5).
__global__ __launch_bounds__(512, 2) void lstm_step(
    const __hip_bfloat16* __restrict__ hin,
    __hip_bfloat16* __restrict__ hout,
    float* __restrict__ cbuf,
    const float* __restrict__ bx,
    const float* __restrict__ Wih,
    const float* __restrict__ bcomb,
    const __hip_bfloat16* __restrict__ wbf,
    int t, int skipmm)
{
  __shared__ short sA[256*64];   // 256 batch rows x 64 k
  __shared__ short sB[256*64];   // (4 gates x 64 hcols) x 64 k
  const int tid = threadIdx.x;
  const int l  = tid & 63, w = tid >> 6;
  const int lo = l & 31,  hi = l >> 5;
  const int wr = w >> 1,  wc = w & 1;    // wave row-quarter / gc-half

  const int orig = blockIdx.x;
  const int swz = (orig & 7)*64 + (orig >> 3);   // XCD-chunked (512 % 8 == 0, bijective)
  const int panel = swz >> 3;            // 0..63 : 256-row panel
  const int cq    = swz & 7;             // 0..7  : 64-hcol quad

  f32x16 acc[4][2] = {};                 // [gate][m]

  if (!skipmm){
    // staging: 2048 A-chunks + 2048 B-chunks of 16B; 4+4 per thread.
    // LDS linear; source pre-swizzled: chunk c -> row=c>>3, slot s=c&7, kc = s ^ (row&7).
    const __hip_bfloat16* asrc[4]; int adst[4];
    const __hip_bfloat16* bsrc[4]; int bdst[4];
    #pragma unroll
    for (int i = 0; i < 4; ++i){
      int c = i*512 + tid;
      int row = c >> 3, s = c & 7;
      int kc = s ^ (row & 7);
      asrc[i] = hin + (size_t)(panel*256 + row)*HDIM + kc*8;
      adst[i] = c*8;
      int g = row >> 6, hcw = row & 63;
      bsrc[i] = wbf + (size_t)(g*HDIM + cq*64 + hcw)*HDIM + kc*8;
      bdst[i] = c*8;
    }
    const int xorv = (lo & 7);
    const int rowA0 = wr*64 + lo, rowA1 = rowA0 + 32;

    for (int kt = 0; kt < 8; ++kt){
      const int k0 = kt*64;
      __syncthreads();
      #pragma unroll
      for (int i = 0; i < 4; ++i) gload16(asrc[i] + k0, &sA[adst[i]]);
      #pragma unroll
      for (int i = 0; i < 4; ++i) gload16(bsrc[i] + k0, &sB[bdst[i]]);
      __syncthreads();
      #pragma unroll
      for (int kk = 0; kk < 4; ++kk){
        const int so = ((kk*2 + hi) ^ xorv) * 8;   // swizzled 16B slot (in shorts)
        s16x8 av0 = *(const s16x8*)&sA[rowA0*64 + so];
        s16x8 av1 = *(const s16x8*)&sA[rowA1*64 + so];
        #pragma unroll
        for (int g = 0; g < 4; ++g){
          s16x8 bv = *(const s16x8*)&sB[(g*64 + wc*32 + lo)*64 + so];
          acc[g][0] = __builtin_amdgcn_mfma_f32_32x32x16_bf16(av0, bv, acc[g][0], 0, 0, 0);
          acc[g][1] = __builtin_amdgcn_mfma_f32_32x32x16_bf16(av1, bv, acc[g][1], 0, 0, 0);
        }
      }
    }
  }

  // ---- epilogue: x-projection + bias + cell update ----
  const int colg = cq*64 + wc*32 + lo;
  float4 wv[4]; float bc4[4];
  #pragma unroll
  for (int g = 0; g < 4; ++g){
    int gc = g*HDIM + colg;
    wv[g]  = *(const float4*)(Wih + (size_t)gc*4);
    bc4[g] = bcomb[gc];
  }
  #pragma unroll
  for (int m = 0; m < 2; ++m){
    #pragma unroll
    for (int q = 0; q < 4; ++q){
      #pragma unroll
      for (int i2 = 0; i2 < 4; ++i2){
        const int reg = q*4 + i2;
        const int r = panel*256 + wr*64 + m*32 + q*8 + hi*4 + i2;
        float4 xv = *(const float4*)(bx + ((size_t)r*TSTEPS + t)*4);
        float pi = acc[0][m][reg] + bc4[0] + xv.x*wv[0].x + xv.y*wv[0].y + xv.z*wv[0].z + xv.w*wv[0].w;
        float pf = acc[1][m][reg] + bc4[1] + xv.x*wv[1].x + xv.y*wv[1].y + xv.z*wv[1].z + xv.w*wv[1].w;
        float pg = acc[2][m][reg] + bc4[2] + xv.x*wv[2].x + xv.y*wv[2].y + xv.z*wv[2].z + xv.w*wv[2].w;
        float po = acc[3][m][reg] + bc4[3] + xv.x*wv[3].x + xv.y*wv[3].y + xv.z*wv[3].z + xv.w*wv[3].w;
        float iv = sigm(pi), fv = sigm(pf), gv = tanhx(pg), ov = sigm(po);
        size_t idx = (size_t)r*HDIM + colg;
        float cold = skipmm ? 0.f : cbuf[idx];   // t=0: c0 = 0 (no memset needed)
        float cn = fv*cold + iv*gv;
        cbuf[idx] = cn;
        hout[idx] = __float2bfloat16(ov*tanhx(cn));
      }
    }
  }
}

__global__ void prep(const float* __restrict__ Whh, const float* __restrict__ W1,
                     const float* __restrict__ bih, const float* __restrict__ bhh,
                     __hip_bfloat16* __restrict__ wbf, __hip_bfloat16* __restrict__ w1bf,
                     float* __restrict__ bcomb){
  int i = blockIdx.x*256 + threadIdx.x;
  if (i < GDIM*HDIM) wbf[i] = __float2bfloat16(Whh[i]);
  if (i < HDIM*HDIM) w1bf[i] = __float2bfloat16(W1[i]);
  if (i < GDIM) bcomb[i] = bih[i] + bhh[i];
}

// x = relu(hT @ W1^T + b1), bf16 MFMA, fp32 out. Block 128x128, wave 32x128.
__global__ __launch_bounds__(256) void mlp1(const __hip_bfloat16* __restrict__ hT,
                                            const __hip_bfloat16* __restrict__ w1bf,
                                            const float* __restrict__ b1, float* __restrict__ xout){
  __shared__ short sA[128*64];
  __shared__ short sB[128*64];
  const int tid = threadIdx.x;
  const int l = tid & 63, w = tid >> 6;
  const int lr = l & 15, lk = l >> 4;
  const int r0 = blockIdx.x * 128, c0 = blockIdx.y * 128;

  f32x4 acc[2][8] = {};
  for (int k0 = 0; k0 < HDIM; k0 += 64){
    __syncthreads();
    #pragma unroll
    for (int i = 0; i < 4; ++i){
      int cch = i*256 + tid;
      int row = cch >> 3, kc = cch & 7;
      int kcs = kc ^ (row & 7);
      gload16(hT + (size_t)(r0 + row)*HDIM + k0 + kcs*8, &sA[cch*8]);
    }
    #pragma unroll
    for (int i = 0; i < 4; ++i){
      int cch = i*256 + tid;
      int row = cch >> 3, kc = cch & 7;
      int kcs = kc ^ (row & 7);
      gload16(w1bf + (size_t)(c0 + row)*HDIM + k0 + kcs*8, &sB[cch*8]);
    }
    __syncthreads();
    #pragma unroll
    for (int kk = 0; kk < 2; ++kk){
      s16x8 av[2];
      #pragma unroll
      for (int m = 0; m < 2; ++m){
        int row = w*32 + m*16 + lr;
        int slot = row*8 + ((kk*4 + lk) ^ (row & 7));
        av[m] = *(const s16x8*)&sA[slot*8];
      }
      #pragma unroll
      for (int n = 0; n < 8; ++n){
        int rB = n*16 + lr;
        int slot = rB*8 + ((kk*4 + lk) ^ (rB & 7));
        s16x8 bv = *(const s16x8*)&sB[slot*8];
        #pragma unroll
        for (int m = 0; m < 2; ++m)
          acc[m][n] = __builtin_amdgcn_mfma_f32_16x16x32_bf16(av[m], bv, acc[m][n], 0, 0, 0);
      }
    }
  }
  #pragma unroll
  for (int m = 0; m < 2; ++m){
    #pragma unroll
    for (int rg = 0; rg < 4; ++rg){
      int r = r0 + w*32 + m*16 + lk*4 + rg;
      #pragma unroll
      for (int n = 0; n < 8; ++n){
        int c = c0 + n*16 + lr;
        float v = acc[m][n][rg] + b1[c];
        xout[(size_t)r*HDIM + c] = v > 0.f ? v : 0.f;
      }
    }
  }
}

// out[b] = x[b,:] . W2[0:512] + a[b]*W2[512] + b2 ; one wave per row
__global__ __launch_bounds__(256) void mlp2(const float* __restrict__ x, const float* __restrict__ a,
                                            const float* __restrict__ W2, const float* __restrict__ b2,
                                            float* __restrict__ out){
  const int wi = threadIdx.x >> 6, l = threadIdx.x & 63;
  const int b = blockIdx.x*4 + wi;
  const float* xr = x + (size_t)b*HDIM;
  float4 v0 = *(const float4*)(xr + l*8);
  float4 v1 = *(const float4*)(xr + l*8 + 4);
  float4 w0 = *(const float4*)(W2 + l*8);
  float4 w1 = *(const float4*)(W2 + l*8 + 4);
  float s = v0.x*w0.x + v0.y*w0.y + v0.z*w0.z + v0.w*w0.w
          + v1.x*w1.x + v1.y*w1.y + v1.z*w1.z + v1.w*w1.w;
  #pragma unroll
  for (int off = 32; off > 0; off >>= 1) s += __shfl_down(s, off);
  if (l == 0) out[b] = s + a[b]*W2[HDIM] + b2[0];
}

extern "C" void kernel_launch(void* const* d_in, const int* in_sizes, int n_in,
                              void* d_out, int out_size, void* d_ws, size_t ws_size,
                              hipStream_t stream){
  const float* bx  = (const float*)d_in[0];
  const float* ba  = (const float*)d_in[1];
  const float* Wih = (const float*)d_in[2];
  const float* Whh = (const float*)d_in[3];
  const float* bih = (const float*)d_in[4];
  const float* bhh = (const float*)d_in[5];
  const float* W1  = (const float*)d_in[6];
  const float* b1  = (const float*)d_in[7];
  const float* W2  = (const float*)d_in[8];
  const float* b2  = (const float*)d_in[9];
  float* out = (float*)d_out;

  char* ws = (char*)d_ws;
  __hip_bfloat16* wbf   = (__hip_bfloat16*)(ws);              // 2 MB
  __hip_bfloat16* w1bf  = (__hip_bfloat16*)(ws + 2097152);    // 512 KB
  float*          bcomb = (float*)(ws + 2621440);             // 8 KB
  __hip_bfloat16* hb0   = (__hip_bfloat16*)(ws + 2629632);    // 16 MB
  __hip_bfloat16* hb1   = (__hip_bfloat16*)(ws + 19406848);   // 16 MB
  float*          cbuf  = (float*)(ws + 36184064);            // 32 MB (end ~66.5 MB)
  float*          xmlp  = cbuf;  // c dead after last step; reuse for MLP activations

  prep<<<4096, 256, 0, stream>>>(Whh, W1, bih, bhh, wbf, w1bf, bcomb);

  for (int t = 0; t < TSTEPS; ++t){
    const __hip_bfloat16* hin = (t & 1) ? hb1 : hb0;
    __hip_bfloat16*      hout = (t & 1) ? hb0 : hb1;
    lstm_step<<<512, 512, 0, stream>>>(hin, hout, cbuf, bx, Wih, bcomb, wbf,
                                       t, (t == 0) ? 1 : 0);
  }
  // t=100 wrote hout = hb1
  mlp1<<<dim3(128, 4), 256, 0, stream>>>(hb1, w1bf, b1, xmlp);
  mlp2<<<4096, 256, 0, stream>>>(xmlp, ba, W2, b2, out);
}